// Round 10
// baseline (305.424 us; speedup 1.0000x reference)
//
#include <hip/hip_runtime.h>
#include <hip/hip_fp16.h>
#include <hip/hip_cooperative_groups.h>
#include <cstdint>
#include <cstddef>

namespace cg = cooperative_groups;

#define N_NODES 50000
#define N_EDGES 800000
#define DIM_IN  128
#define DIM_OUT 64

#define BSHIFT  6                                  // 64 nodes per bucket
#define BNODES  64
#define NB      1024                               // padded bucket count (pow2)
#define NBK     ((N_NODES + BNODES - 1) / BNODES)  // 782 buckets used
#define EB      4096                               // edges per tile
#define SORTB   ((N_EDGES + EB - 1) / EB)          // 196 tiles
#define NE4     (N_EDGES / 4)                      // 200000 int4 edge groups
#define CAPB    1280                               // slots/bucket (mean 781, sd 28)
#define GROWS   128                                // gemm rows per unit
#define GEMMB   ((N_NODES + GROWS - 1) / GROWS)    // 391 gemm units
#define P1UNITS (SORTB + GEMMB)                    // 587 phase-1 units
#define NGROUP  (N_NODES / 16)                     // 3125 kE node-groups

typedef _Float16 f16x8 __attribute__((ext_vector_type(8)));
typedef _Float16 f16x4 __attribute__((ext_vector_type(4)));
typedef float    f32x4 __attribute__((ext_vector_type(4)));

// ---------------------------------------------------------------------------
// Single cooperative kernel. Phases separated by grid.sync():
//   0: zero gcnt
//   1: [tiles 0..195] bucket-scatter front-end  ||  [units 196..586] MFMA gemm
//      (gemm writes h UNSCALED -> independent of the sort pipeline)
//   2: per-bucket counting sort -> csr/nodeoff2, then h *= dinv in place
//   3: CSR gather + bias + log_softmax (quarter-wave per node)
// ---------------------------------------------------------------------------
__global__ __launch_bounds__(256, 3) void kFused(
        const int* __restrict__ ei,
        int* __restrict__ gcnt,
        unsigned* __restrict__ pairs,
        const float* __restrict__ x,
        const float* __restrict__ W,
        unsigned short* __restrict__ csr,
        int2* __restrict__ nodeoff2,
        __half* __restrict__ h,
        const float* __restrict__ bvec,
        float* __restrict__ out) {
    cg::grid_group grid = cg::this_grid();
    const int t = threadIdx.x;
    const int blk = blockIdx.x;
    const int gsz = (int)gridDim.x;

    __shared__ int sA[NB];   // kF: hcnt | kSort: cnt[64] cur[64] sdinv[64]
    __shared__ int sB[NB];   // kF: cur

    // ---- phase 0: zero the 1024 global bucket counters ----
    if (blk < 4) gcnt[blk * 256 + t] = 0;
    grid.sync();

    // ---- phase 1: kF tiles || gemm units, work-strided ----
    for (int u = blk; u < P1UNITS; u += gsz) {
        if (u < SORTB) {
            // ---- front-end tile u: histogram -> reserve -> scatter ----
            __syncthreads();                         // sA/sB reuse guard
            for (int i = t; i < NB; i += 256) sA[i] = 0;
            __syncthreads();
            const int4* src4 = (const int4*)ei;
            const int4* dst4 = (const int4*)(ei + N_EDGES);
            const int g0 = u * (EB / 4);
#pragma unroll
            for (int it = 0; it < EB / 1024; ++it) {
                const int g = g0 + it * 256 + t;
                if (g < NE4) {
                    const int4 d = dst4[g];
                    atomicAdd(&sA[d.x >> BSHIFT], 1);
                    atomicAdd(&sA[d.y >> BSHIFT], 1);
                    atomicAdd(&sA[d.z >> BSHIFT], 1);
                    atomicAdd(&sA[d.w >> BSHIFT], 1);
                }
            }
            __syncthreads();
            for (int i = t; i < NB; i += 256) {      // reserve runs (1 atomic each)
                const int c = sA[i];
                const int base = c ? atomicAdd(&gcnt[i], c) : 0;
                sB[i] = i * CAPB + base;
            }
            __syncthreads();
#pragma unroll
            for (int it = 0; it < EB / 1024; ++it) { // scatter (L2-hot reread)
                const int g = g0 + it * 256 + t;
                if (g < NE4) {
                    const int4 sv = src4[g];
                    const int4 dv = dst4[g];
                    int b, p;
                    b = dv.x >> BSHIFT; p = atomicAdd(&sB[b], 1);
                    if (p < b * CAPB + CAPB) pairs[p] = ((unsigned)sv.x << 16) | (unsigned)dv.x;
                    b = dv.y >> BSHIFT; p = atomicAdd(&sB[b], 1);
                    if (p < b * CAPB + CAPB) pairs[p] = ((unsigned)sv.y << 16) | (unsigned)dv.y;
                    b = dv.z >> BSHIFT; p = atomicAdd(&sB[b], 1);
                    if (p < b * CAPB + CAPB) pairs[p] = ((unsigned)sv.z << 16) | (unsigned)dv.z;
                    b = dv.w >> BSHIFT; p = atomicAdd(&sB[b], 1);
                    if (p < b * CAPB + CAPB) pairs[p] = ((unsigned)sv.w << 16) | (unsigned)dv.w;
                }
            }
            __syncthreads();
        } else {
            // ---- gemm unit: h[n,:] = half(x[n,:] @ W), UNSCALED ----
            // MFMA 16x16x32_f16: A[m=lane&15][k=quad*8+j]; B[k][n=lane&15];
            // C/D: row=quad*4+reg, col=lane&15 (validated R6-R9).
            const int w = t >> 6;
            const int l = t & 63;
            const int q = l >> 4;
            const int m16 = l & 15;

            f16x8 bf[4][4];
#pragma unroll
            for (int kc = 0; kc < 4; ++kc)
#pragma unroll
                for (int ct = 0; ct < 4; ++ct) {
                    const float* wp = W + (size_t)(kc * 32 + q * 8) * DIM_OUT + ct * 16 + m16;
                    f16x8 v;
#pragma unroll
                    for (int j = 0; j < 8; ++j) v[j] = (_Float16)wp[(size_t)j * DIM_OUT];
                    bf[kc][ct] = v;
                }

            const int base = (u - SORTB) * GROWS + w * 32;
#pragma unroll
            for (int rt = 0; rt < 2; ++rt) {
                const int m0 = base + rt * 16;
                int mrow = m0 + m16;
                if (mrow >= N_NODES) mrow = N_NODES - 1;   // clamp (stores guarded)

                f16x8 af[4];
#pragma unroll
                for (int kc = 0; kc < 4; ++kc) {
                    const float4* xp = (const float4*)(x + (size_t)mrow * DIM_IN + kc * 32 + q * 8);
                    const float4 p0 = xp[0], p1 = xp[1];
                    f16x8 a;
                    a[0] = (_Float16)p0.x; a[1] = (_Float16)p0.y;
                    a[2] = (_Float16)p0.z; a[3] = (_Float16)p0.w;
                    a[4] = (_Float16)p1.x; a[5] = (_Float16)p1.y;
                    a[6] = (_Float16)p1.z; a[7] = (_Float16)p1.w;
                    af[kc] = a;
                }

                f32x4 acc[4];
#pragma unroll
                for (int ct = 0; ct < 4; ++ct) acc[ct] = (f32x4){0.f, 0.f, 0.f, 0.f};
#pragma unroll
                for (int kc = 0; kc < 4; ++kc)
#pragma unroll
                    for (int ct = 0; ct < 4; ++ct)
                        acc[ct] = __builtin_amdgcn_mfma_f32_16x16x32_f16(af[kc], bf[kc][ct], acc[ct], 0, 0, 0);

#pragma unroll
                for (int reg = 0; reg < 4; ++reg) {
                    const int r = m0 + q * 4 + reg;
                    if (r < N_NODES) {
#pragma unroll
                        for (int ct = 0; ct < 4; ++ct)
                            h[(size_t)r * DIM_OUT + ct * 16 + m16] = __float2half(acc[ct][reg]);
                    }
                }
            }
        }
    }
    grid.sync();

    // ---- phase 2: per-bucket counting sort + in-place h-scale ----
    {
        int* cnt = sA;
        int* cur = sA + BNODES;
        float* sdinv = (float*)(sA + 2 * BNODES);
        f16x4* h4w = (f16x4*)h;

        for (int bb = blk; bb < NBK; bb += gsz) {
            __syncthreads();                         // sA reuse guard
            if (t < BNODES) cnt[t] = 0;
            __syncthreads();

            const int eb = bb * CAPB;
            const int count = min(gcnt[bb], CAPB);   // clamp matches kF guard
            const int ee = eb + count;

            {
                int i = eb + t;
                for (; i + 768 < ee; i += 1024) {
                    const unsigned p0 = pairs[i];
                    const unsigned p1 = pairs[i + 256];
                    const unsigned p2 = pairs[i + 512];
                    const unsigned p3 = pairs[i + 768];
                    atomicAdd(&cnt[p0 & (BNODES - 1)], 1);
                    atomicAdd(&cnt[p1 & (BNODES - 1)], 1);
                    atomicAdd(&cnt[p2 & (BNODES - 1)], 1);
                    atomicAdd(&cnt[p3 & (BNODES - 1)], 1);
                }
                for (; i < ee; i += 256) atomicAdd(&cnt[pairs[i] & (BNODES - 1)], 1);
            }
            __syncthreads();

            if (t < 64) {                            // wave 0: 64-wide shuffle scan
                const int lane = t;
                const int v = cnt[lane];
                int xs = v;
#pragma unroll
                for (int off = 1; off < 64; off <<= 1) {
                    int y = __shfl_up(xs, off);
                    if (lane >= off) xs += y;
                }
                const int excl = xs - v;
                cur[lane] = eb + excl;
                sdinv[lane] = rsqrtf((float)(v + 1));
                const int n = (bb << BSHIFT) + lane;
                if (n < N_NODES) nodeoff2[n] = make_int2(eb + excl, v);
            }
            __syncthreads();

            // in-place h-scale for this bucket's 64 nodes (16 f16x4 per row)
            for (int idx = t; idx < BNODES * 16; idx += 256) {
                const int r = idx >> 4;
                const int n = (bb << BSHIFT) + r;
                if (n < N_NODES) {
                    const float d = sdinv[r];
                    f16x4 v = h4w[n * 16 + (idx & 15)];
                    v[0] = (_Float16)((float)v[0] * d);
                    v[1] = (_Float16)((float)v[1] * d);
                    v[2] = (_Float16)((float)v[2] * d);
                    v[3] = (_Float16)((float)v[3] * d);
                    h4w[n * 16 + (idx & 15)] = v;
                }
            }

            {
                int i = eb + t;
                for (; i + 768 < ee; i += 1024) {
                    const unsigned p0 = pairs[i];
                    const unsigned p1 = pairs[i + 256];
                    const unsigned p2 = pairs[i + 512];
                    const unsigned p3 = pairs[i + 768];
                    int q;
                    q = atomicAdd(&cur[p0 & (BNODES - 1)], 1); csr[q] = (unsigned short)(p0 >> 16);
                    q = atomicAdd(&cur[p1 & (BNODES - 1)], 1); csr[q] = (unsigned short)(p1 >> 16);
                    q = atomicAdd(&cur[p2 & (BNODES - 1)], 1); csr[q] = (unsigned short)(p2 >> 16);
                    q = atomicAdd(&cur[p3 & (BNODES - 1)], 1); csr[q] = (unsigned short)(p3 >> 16);
                }
                for (; i < ee; i += 256) {
                    const unsigned p = pairs[i];
                    const int q = atomicAdd(&cur[p & (BNODES - 1)], 1);
                    csr[q] = (unsigned short)(p >> 16);
                }
            }
        }
    }
    grid.sync();

    // ---- phase 3: CSR gather + bias + log_softmax (quarter-wave per node) ----
    {
        const int qw = t >> 4, sl = t & 15;
        const f16x4* __restrict__ h4 = (const f16x4*)h;
        const float4 bias = *(const float4*)&bvec[4 * sl];

        for (int g = blk; g < NGROUP; g += gsz) {
            const int n = g * 16 + qw;               // < 50000 always
            const int2 off = nodeoff2[n];
            const int s0 = off.x, s1 = off.x + off.y;

            const f16x4 hv = h4[n * 16 + sl];        // self-loop term (scaled)
            float a0f = (float)hv[0], a1f = (float)hv[1], a2f = (float)hv[2], a3f = (float)hv[3];

            int i = s0;
            for (; i + 4 <= s1; i += 4) {
                const int c0 = csr[i + 0];
                const int c1 = csr[i + 1];
                const int c2 = csr[i + 2];
                const int c3 = csr[i + 3];
                const f16x4 v0 = h4[c0 * 16 + sl];
                const f16x4 v1 = h4[c1 * 16 + sl];
                const f16x4 v2 = h4[c2 * 16 + sl];
                const f16x4 v3 = h4[c3 * 16 + sl];
                a0f += (float)v0[0] + (float)v1[0] + (float)v2[0] + (float)v3[0];
                a1f += (float)v0[1] + (float)v1[1] + (float)v2[1] + (float)v3[1];
                a2f += (float)v0[2] + (float)v1[2] + (float)v2[2] + (float)v3[2];
                a3f += (float)v0[3] + (float)v1[3] + (float)v2[3] + (float)v3[3];
            }
            for (; i < s1; ++i) {
                const f16x4 v0 = h4[csr[i] * 16 + sl];
                a0f += (float)v0[0]; a1f += (float)v0[1]; a2f += (float)v0[2]; a3f += (float)v0[3];
            }

            const float di = rsqrtf((float)(off.y + 1));
            float v0 = a0f * di + bias.x;
            float v1 = a1f * di + bias.y;
            float v2 = a2f * di + bias.z;
            float v3 = a3f * di + bias.w;

            float m = fmaxf(fmaxf(v0, v1), fmaxf(v2, v3));
#pragma unroll
            for (int o = 8; o > 0; o >>= 1) m = fmaxf(m, __shfl_xor(m, o));
            float s = __expf(v0 - m) + __expf(v1 - m) + __expf(v2 - m) + __expf(v3 - m);
#pragma unroll
            for (int o = 8; o > 0; o >>= 1) s += __shfl_xor(s, o);
            const float ls = __logf(s);

            float4 o4;
            o4.x = v0 - m - ls; o4.y = v1 - m - ls; o4.z = v2 - m - ls; o4.w = v3 - m - ls;
            *(float4*)&out[(size_t)n * DIM_OUT + 4 * sl] = o4;
        }
    }
}

// ---------------------------------------------------------------------------
extern "C" void kernel_launch(void* const* d_in, const int* in_sizes, int n_in,
                              void* d_out, int out_size, void* d_ws, size_t ws_size,
                              hipStream_t stream) {
    const float* x  = (const float*)d_in[0];
    const int*   ei = (const int*)d_in[1];   // [2, E]: row0 = src, row1 = dst
    const float* W  = (const float*)d_in[2];
    const float* b  = (const float*)d_in[3];
    float* out = (float*)d_out;

    // workspace (~14 MB of the 256 MB ws):
    char* ws = (char*)d_ws;
    __half*         h        = (__half*)ws;         ws += (size_t)N_NODES * DIM_OUT * sizeof(__half);
    unsigned*       pairs    = (unsigned*)ws;       ws += (size_t)NB * CAPB * sizeof(unsigned);
    unsigned short* csr      = (unsigned short*)ws; ws += (size_t)NB * CAPB * sizeof(unsigned short);
    int2*           nodeoff2 = (int2*)ws;           ws += (size_t)N_NODES * sizeof(int2);
    int*            gcnt     = (int*)ws;            ws += (size_t)NB * sizeof(int);

    // size grid to guaranteed co-residency (clamped to 3 blocks/CU x 256 CUs);
    // all phases are work-strided, so any grid >= 256 is correct.
    int maxb = 0;
    (void)hipOccupancyMaxActiveBlocksPerMultiprocessor(&maxb, kFused, 256, 0);
    if (maxb < 1) maxb = 1;
    if (maxb > 3) maxb = 3;
    const int grid = maxb * 256;

    void* args[] = {(void*)&ei, (void*)&gcnt, (void*)&pairs, (void*)&x, (void*)&W,
                    (void*)&csr, (void*)&nodeoff2, (void*)&h, (void*)&b, (void*)&out};
    (void)hipLaunchCooperativeKernel((void*)kFused, dim3(grid), dim3(256),
                                     args, 0, stream);
}

// Round 11
// 115.256 us; speedup vs baseline: 2.6500x; 2.6500x over previous
//
#include <hip/hip_runtime.h>
#include <hip/hip_fp16.h>
#include <cstdint>
#include <cstddef>

#define N_NODES 50000
#define N_EDGES 800000
#define DIM_IN  128
#define DIM_OUT 64

#define BSHIFT  6                                  // 64 nodes per bucket
#define BNODES  64
#define NB      1024                               // padded bucket count (pow2)
#define NBK     ((N_NODES + BNODES - 1) / BNODES)  // 782 buckets used
#define EB      4096                               // edges per tile
#define SORTB   ((N_EDGES + EB - 1) / EB)          // 196 tiles
#define NE4     (N_EDGES / 4)                      // 200000 int4 edge groups
#define CAPB    1280                               // slots/bucket (mean 781, sd 28)
#define GROWS   128                                // gemm rows per unit
#define GEMMB   ((N_NODES + GROWS - 1) / GROWS)    // 391 gemm units
#define NEGRP   ((N_NODES + 31) / 32)              // 1563 kE blocks (32 nodes each)

typedef _Float16 f16x8 __attribute__((ext_vector_type(8)));
typedef _Float16 f16x4 __attribute__((ext_vector_type(4)));
typedef float    f32x4 __attribute__((ext_vector_type(4)));

// ---------------------------------------------------------------------------
// Zero the 1024 global bucket counters.
// ---------------------------------------------------------------------------
__global__ __launch_bounds__(256) void k_zero(int* __restrict__ gcnt) {
    const int i = blockIdx.x * 256 + threadIdx.x;
    if (i < NB) gcnt[i] = 0;
}

// ---------------------------------------------------------------------------
// FG: dual-role dispatch, NO grid sync (the two roles are independent).
//   blocks 0..SORTB-1   : bucket-scatter front-end (histogram/reserve/scatter)
//   blocks SORTB..586   : MFMA gemm writing UNSCALED h = half(x @ W)
// Each path keeps its own occupancy profile; they overlap on different pipes.
// ---------------------------------------------------------------------------
__global__ __launch_bounds__(256) void kFG(const int* __restrict__ ei,
                                           int* __restrict__ gcnt,
                                           unsigned* __restrict__ pairs,
                                           const float* __restrict__ x,
                                           const float* __restrict__ W,
                                           __half* __restrict__ h) {
    const int t = threadIdx.x;
    if (blockIdx.x < SORTB) {
        // ---- front-end tile: histogram -> reserve -> scatter ----
        __shared__ int hcnt[NB];
        __shared__ int cur[NB];
        const int blk = blockIdx.x;
        for (int i = t; i < NB; i += 256) hcnt[i] = 0;
        __syncthreads();
        const int4* src4 = (const int4*)ei;
        const int4* dst4 = (const int4*)(ei + N_EDGES);
        const int g0 = blk * (EB / 4);
#pragma unroll
        for (int it = 0; it < EB / 1024; ++it) {
            const int g = g0 + it * 256 + t;
            if (g < NE4) {
                const int4 d = dst4[g];
                atomicAdd(&hcnt[d.x >> BSHIFT], 1);
                atomicAdd(&hcnt[d.y >> BSHIFT], 1);
                atomicAdd(&hcnt[d.z >> BSHIFT], 1);
                atomicAdd(&hcnt[d.w >> BSHIFT], 1);
            }
        }
        __syncthreads();
        for (int i = t; i < NB; i += 256) {          // reserve runs (1 atomic each)
            const int c = hcnt[i];
            const int base = c ? atomicAdd(&gcnt[i], c) : 0;
            cur[i] = i * CAPB + base;
        }
        __syncthreads();
#pragma unroll
        for (int it = 0; it < EB / 1024; ++it) {     // scatter (L2-hot reread)
            const int g = g0 + it * 256 + t;
            if (g < NE4) {
                const int4 sv = src4[g];
                const int4 dv = dst4[g];
                int b, p;
                b = dv.x >> BSHIFT; p = atomicAdd(&cur[b], 1);
                if (p < b * CAPB + CAPB) pairs[p] = ((unsigned)sv.x << 16) | (unsigned)dv.x;
                b = dv.y >> BSHIFT; p = atomicAdd(&cur[b], 1);
                if (p < b * CAPB + CAPB) pairs[p] = ((unsigned)sv.y << 16) | (unsigned)dv.y;
                b = dv.z >> BSHIFT; p = atomicAdd(&cur[b], 1);
                if (p < b * CAPB + CAPB) pairs[p] = ((unsigned)sv.z << 16) | (unsigned)dv.z;
                b = dv.w >> BSHIFT; p = atomicAdd(&cur[b], 1);
                if (p < b * CAPB + CAPB) pairs[p] = ((unsigned)sv.w << 16) | (unsigned)dv.w;
            }
        }
    } else {
        // ---- gemm unit: h[n,:] = half(x[n,:] @ W), UNSCALED ----
        // MFMA 16x16x32_f16: A[m=lane&15][k=quad*8+j]; B[k][n=lane&15];
        // C/D: row=quad*4+reg, col=lane&15 (validated R6-R10).
        const int u = blockIdx.x - SORTB;
        const int w = t >> 6;
        const int l = t & 63;
        const int q = l >> 4;
        const int m16 = l & 15;

        f16x8 bf[4][4];
#pragma unroll
        for (int kc = 0; kc < 4; ++kc)
#pragma unroll
            for (int ct = 0; ct < 4; ++ct) {
                const float* wp = W + (size_t)(kc * 32 + q * 8) * DIM_OUT + ct * 16 + m16;
                f16x8 v;
#pragma unroll
                for (int j = 0; j < 8; ++j) v[j] = (_Float16)wp[(size_t)j * DIM_OUT];
                bf[kc][ct] = v;
            }

        const int base = u * GROWS + w * 32;
#pragma unroll
        for (int rt = 0; rt < 2; ++rt) {
            const int m0 = base + rt * 16;
            int mrow = m0 + m16;
            if (mrow >= N_NODES) mrow = N_NODES - 1;   // clamp (stores guarded)

            f16x8 af[4];
#pragma unroll
            for (int kc = 0; kc < 4; ++kc) {
                const float4* xp = (const float4*)(x + (size_t)mrow * DIM_IN + kc * 32 + q * 8);
                const float4 p0 = xp[0], p1 = xp[1];
                f16x8 a;
                a[0] = (_Float16)p0.x; a[1] = (_Float16)p0.y;
                a[2] = (_Float16)p0.z; a[3] = (_Float16)p0.w;
                a[4] = (_Float16)p1.x; a[5] = (_Float16)p1.y;
                a[6] = (_Float16)p1.z; a[7] = (_Float16)p1.w;
                af[kc] = a;
            }

            f32x4 acc[4];
#pragma unroll
            for (int ct = 0; ct < 4; ++ct) acc[ct] = (f32x4){0.f, 0.f, 0.f, 0.f};
#pragma unroll
            for (int kc = 0; kc < 4; ++kc)
#pragma unroll
                for (int ct = 0; ct < 4; ++ct)
                    acc[ct] = __builtin_amdgcn_mfma_f32_16x16x32_f16(af[kc], bf[kc][ct], acc[ct], 0, 0, 0);

#pragma unroll
            for (int reg = 0; reg < 4; ++reg) {
                const int r = m0 + q * 4 + reg;
                if (r < N_NODES) {
#pragma unroll
                    for (int ct = 0; ct < 4; ++ct)
                        h[(size_t)r * DIM_OUT + ct * 16 + m16] = __float2half(acc[ct][reg]);
                }
            }
        }
    }
}

// ---------------------------------------------------------------------------
// Sort+Scale: per bucket (64 nodes), node-granular counting sort into padded
// csr, emitting nodeoff2 = (start, deg); then h *= rsqrt(deg+1) in place.
// ---------------------------------------------------------------------------
__global__ __launch_bounds__(256) void kSort(const unsigned* __restrict__ pairs,
                                             const int* __restrict__ gcnt,
                                             unsigned short* __restrict__ csr,
                                             int2* __restrict__ nodeoff2,
                                             __half* __restrict__ h) {
    __shared__ int cnt[BNODES];
    __shared__ int cur[BNODES];
    __shared__ float sdinv[BNODES];
    const int b = blockIdx.x, t = threadIdx.x;
    const int eb = b * CAPB;
    const int count = min(gcnt[b], CAPB);            // clamp matches kFG guard
    const int ee = eb + count;

    if (t < BNODES) cnt[t] = 0;
    __syncthreads();

    {
        int i = eb + t;
        for (; i + 768 < ee; i += 1024) {
            const unsigned p0 = pairs[i];
            const unsigned p1 = pairs[i + 256];
            const unsigned p2 = pairs[i + 512];
            const unsigned p3 = pairs[i + 768];
            atomicAdd(&cnt[p0 & (BNODES - 1)], 1);
            atomicAdd(&cnt[p1 & (BNODES - 1)], 1);
            atomicAdd(&cnt[p2 & (BNODES - 1)], 1);
            atomicAdd(&cnt[p3 & (BNODES - 1)], 1);
        }
        for (; i < ee; i += 256) atomicAdd(&cnt[pairs[i] & (BNODES - 1)], 1);
    }
    __syncthreads();

    if (t < 64) {                        // wave 0: 64-wide shuffle scan
        const int lane = t;
        const int v = cnt[lane];
        int xs = v;
#pragma unroll
        for (int off = 1; off < 64; off <<= 1) {
            int y = __shfl_up(xs, off);
            if (lane >= off) xs += y;
        }
        const int excl = xs - v;
        cur[lane] = eb + excl;
        sdinv[lane] = rsqrtf((float)(v + 1));
        const int n = (b << BSHIFT) + lane;
        if (n < N_NODES) nodeoff2[n] = make_int2(eb + excl, v);
    }
    __syncthreads();

    // in-place h-scale for this bucket's 64 nodes (8 f16x8 per row)
    {
        f16x8* h8w = (f16x8*)h;
        for (int idx = t; idx < BNODES * 8; idx += 256) {
            const int r = idx >> 3;
            const int n = (b << BSHIFT) + r;
            if (n < N_NODES) {
                const float d = sdinv[r];
                f16x8 v = h8w[n * 8 + (idx & 7)];
#pragma unroll
                for (int j = 0; j < 8; ++j) v[j] = (_Float16)((float)v[j] * d);
                h8w[n * 8 + (idx & 7)] = v;
            }
        }
    }

    {
        int i = eb + t;
        for (; i + 768 < ee; i += 1024) {
            const unsigned p0 = pairs[i];
            const unsigned p1 = pairs[i + 256];
            const unsigned p2 = pairs[i + 512];
            const unsigned p3 = pairs[i + 768];
            int q;
            q = atomicAdd(&cur[p0 & (BNODES - 1)], 1); csr[q] = (unsigned short)(p0 >> 16);
            q = atomicAdd(&cur[p1 & (BNODES - 1)], 1); csr[q] = (unsigned short)(p1 >> 16);
            q = atomicAdd(&cur[p2 & (BNODES - 1)], 1); csr[q] = (unsigned short)(p2 >> 16);
            q = atomicAdd(&cur[p3 & (BNODES - 1)], 1); csr[q] = (unsigned short)(p3 >> 16);
        }
        for (; i < ee; i += 256) {
            const unsigned p = pairs[i];
            const int q = atomicAdd(&cur[p & (BNODES - 1)], 1);
            csr[q] = (unsigned short)(p >> 16);
        }
    }
}

// ---------------------------------------------------------------------------
// E: CSR gather + bias + log_softmax. EIGHTH-wave per node: 8 lanes, each
// lane = 8 channels via one 16 B f16x8 load. 32 nodes/block, 1563 blocks;
// 4-deep unroll -> 32 outstanding gather loads per wave.
// ---------------------------------------------------------------------------
__global__ __launch_bounds__(256) void kE_agg(const int2* __restrict__ nodeoff2,
                                              const unsigned short* __restrict__ csr,
                                              const __half* __restrict__ h,
                                              const float* __restrict__ bvec,
                                              float* __restrict__ out) {
    const int t = threadIdx.x;
    const int ew = t >> 3, sl = t & 7;       // eighth-wave id / sub-lane
    const int n = blockIdx.x * 32 + ew;
    if (n >= N_NODES) return;                // unit-uniform guard
    const f16x8* __restrict__ h8 = (const f16x8*)h;

    const int2 off = nodeoff2[n];
    const int s0 = off.x, s1 = off.x + off.y;

    const f16x8 hv = h8[n * 8 + sl];         // self-loop term (scaled)
    float a[8];
#pragma unroll
    for (int j = 0; j < 8; ++j) a[j] = (float)hv[j];

    int i = s0;
    for (; i + 4 <= s1; i += 4) {
        const int c0 = csr[i + 0];
        const int c1 = csr[i + 1];
        const int c2 = csr[i + 2];
        const int c3 = csr[i + 3];
        const f16x8 v0 = h8[c0 * 8 + sl];
        const f16x8 v1 = h8[c1 * 8 + sl];
        const f16x8 v2 = h8[c2 * 8 + sl];
        const f16x8 v3 = h8[c3 * 8 + sl];
#pragma unroll
        for (int j = 0; j < 8; ++j)
            a[j] += (float)v0[j] + (float)v1[j] + (float)v2[j] + (float)v3[j];
    }
    for (; i < s1; ++i) {
        const f16x8 v0 = h8[csr[i] * 8 + sl];
#pragma unroll
        for (int j = 0; j < 8; ++j) a[j] += (float)v0[j];
    }

    const float4 b0 = *(const float4*)&bvec[8 * sl];
    const float4 b1 = *(const float4*)&bvec[8 * sl + 4];
    const float di = rsqrtf((float)(off.y + 1));
    float v[8];
    v[0] = a[0] * di + b0.x; v[1] = a[1] * di + b0.y;
    v[2] = a[2] * di + b0.z; v[3] = a[3] * di + b0.w;
    v[4] = a[4] * di + b1.x; v[5] = a[5] * di + b1.y;
    v[6] = a[6] * di + b1.z; v[7] = a[7] * di + b1.w;

    float m = v[0];
#pragma unroll
    for (int j = 1; j < 8; ++j) m = fmaxf(m, v[j]);
#pragma unroll
    for (int o = 4; o > 0; o >>= 1) m = fmaxf(m, __shfl_xor(m, o));
    float s = 0.f;
#pragma unroll
    for (int j = 0; j < 8; ++j) s += __expf(v[j] - m);
#pragma unroll
    for (int o = 4; o > 0; o >>= 1) s += __shfl_xor(s, o);
    const float ls = m + __logf(s);

    float4 o0, o1;
    o0.x = v[0] - ls; o0.y = v[1] - ls; o0.z = v[2] - ls; o0.w = v[3] - ls;
    o1.x = v[4] - ls; o1.y = v[5] - ls; o1.z = v[6] - ls; o1.w = v[7] - ls;
    *(float4*)&out[(size_t)n * DIM_OUT + 8 * sl]     = o0;
    *(float4*)&out[(size_t)n * DIM_OUT + 8 * sl + 4] = o1;
}

// ---------------------------------------------------------------------------
extern "C" void kernel_launch(void* const* d_in, const int* in_sizes, int n_in,
                              void* d_out, int out_size, void* d_ws, size_t ws_size,
                              hipStream_t stream) {
    const float* x  = (const float*)d_in[0];
    const int*   ei = (const int*)d_in[1];   // [2, E]: row0 = src, row1 = dst
    const float* W  = (const float*)d_in[2];
    const float* b  = (const float*)d_in[3];
    float* out = (float*)d_out;

    // workspace (~14 MB of the 256 MB ws):
    char* ws = (char*)d_ws;
    __half*         h        = (__half*)ws;         ws += (size_t)N_NODES * DIM_OUT * sizeof(__half);
    unsigned*       pairs    = (unsigned*)ws;       ws += (size_t)NB * CAPB * sizeof(unsigned);
    unsigned short* csr      = (unsigned short*)ws; ws += (size_t)NB * CAPB * sizeof(unsigned short);
    int2*           nodeoff2 = (int2*)ws;           ws += (size_t)N_NODES * sizeof(int2);
    int*            gcnt     = (int*)ws;            ws += (size_t)NB * sizeof(int);

    k_zero<<<(NB + 255) / 256, 256, 0, stream>>>(gcnt);
    kFG   <<<SORTB + GEMMB, 256, 0, stream>>>(ei, gcnt, pairs, x, W, h);
    kSort <<<NBK, 256, 0, stream>>>(pairs, gcnt, csr, nodeoff2, h);
    kE_agg<<<NEGRP, 256, 0, stream>>>(nodeoff2, csr, h, b, out);
}